// Round 9
// baseline (361.644 us; speedup 1.0000x reference)
//
#include <hip/hip_runtime.h>
#include <hip/hip_bf16.h>

// Problem constants
#define BATCH 4
#define SEQ   2048
#define DIM   1024      // D = H*HDIM
#define NHEAD 16
#define HDIM  64
#define EPS_LN 1e-5f
// 1/sqrt(64) * log2(e): folded into Q projection so attention can use exp2
#define QSCALE 0.18033688011112042f

typedef __attribute__((ext_vector_type(8))) short short8;   // 8 bf16 = 4 VGPR
typedef __attribute__((ext_vector_type(4))) float f32x4;    // 16x16 MFMA acc
typedef __attribute__((ext_vector_type(16))) float f32x16;  // 32x32 MFMA acc
typedef __attribute__((ext_vector_type(4))) unsigned uint32x4;

__device__ __forceinline__ unsigned short f2bf(float x) {
    __hip_bfloat16 h = __float2bfloat16(x);
    return *reinterpret_cast<unsigned short*>(&h);
}
__device__ __forceinline__ unsigned int pack2bf(float a, float b) {
    __hip_bfloat162 h = __float22bfloat162_rn(float2{a, b});
    return *reinterpret_cast<unsigned int*>(&h);
}

// gfx950 register-pair lane swap (both operands read-modify-write):
// v_permlane32_swap_b32: a' = {a[0:31], b[0:31]}, b' = {a[32:63], b[32:63]}
__device__ __forceinline__ void pl32_swap(unsigned& a, unsigned& b) {
    asm("v_permlane32_swap_b32 %0, %1" : "+v"(a), "+v"(b));
}

// async 16B global -> LDS (per-lane gptr; LDS dest must be wave-uniform-base + lane*16)
__device__ __forceinline__ void gl_lds16(const void* g, void* l) {
    __builtin_amdgcn_global_load_lds(
        (const __attribute__((address_space(1))) unsigned int*)g,
        (__attribute__((address_space(3))) unsigned int*)l,
        16, 0, 0);
}

// ---------------- prep: 4 weight transposes (z=0..3) + queries convert (z=4) ----------------
__global__ __launch_bounds__(256) void prep_kernel(const float* __restrict__ W0,
                                                   const float* __restrict__ W1,
                                                   const float* __restrict__ W2,
                                                   const float* __restrict__ W3,
                                                   const float* __restrict__ queries,
                                                   unsigned short* __restrict__ Wqkvt,
                                                   unsigned short* __restrict__ Wot,
                                                   unsigned short* __restrict__ qout)
{
    const int z = blockIdx.z;
    const int t = threadIdx.x;

    if (z == 4) {
        // bulk fp32 -> bf16 convert of queries
        const int nthr = 16 * 16 * 256;            // 65536
        int i = (blockIdx.y * 16 + blockIdx.x) * 256 + t;
        for (int it = 0; it < (BATCH * SEQ * DIM / 4) / nthr; it++, i += nthr) {
            float4 v = ((const float4*)queries)[i];
            ushort4 u;
            u.x = f2bf(v.x); u.y = f2bf(v.y); u.z = f2bf(v.z); u.w = f2bf(v.w);
            ((ushort4*)qout)[i] = u;
        }
        return;
    }

    __shared__ float Ts[64][65];
    const float* W = (z == 0) ? W0 : (z == 1) ? W1 : (z == 2) ? W2 : W3;
    unsigned short* Wt = (z == 3) ? Wot : (Wqkvt + (size_t)z * DIM * DIM);

    const int k0 = blockIdx.y * 64, n0 = blockIdx.x * 64;
    const int lr = t >> 2, lq = t & 3;

#pragma unroll
    for (int i = 0; i < 4; i++) {
        float4 v = *(const float4*)(W + (size_t)(k0 + lr) * DIM + n0 + (lq * 4 + i) * 4);
        Ts[lr][(lq * 4 + i) * 4 + 0] = v.x;
        Ts[lr][(lq * 4 + i) * 4 + 1] = v.y;
        Ts[lr][(lq * 4 + i) * 4 + 2] = v.z;
        Ts[lr][(lq * 4 + i) * 4 + 3] = v.w;
    }
    __syncthreads();
#pragma unroll
    for (int i = 0; i < 4; i++) {
        const int c = lq * 16 + i * 4;
        ushort4 u;
        u.x = f2bf(Ts[c + 0][lr]);
        u.y = f2bf(Ts[c + 1][lr]);
        u.z = f2bf(Ts[c + 2][lr]);
        u.w = f2bf(Ts[c + 3][lr]);
        *(ushort4*)(Wt + (size_t)(n0 + lr) * DIM + k0 + c) = u;
    }
}

// ---------------- fused QKV GEMM: [8192,1024] @ [3072,1024]^T ----------------
// sector 0: Qbf natural bf16, (acc+bq)*QSCALE
// sector 1: Kbf natural bf16, acc+bk
// sector 2: Vtb transposed-per-head: Vt[b][h][d][l], acc+bv
__global__ __launch_bounds__(256) void gemm_qkv(const unsigned short* __restrict__ A,
                                                const unsigned short* __restrict__ Bt,
                                                const float* __restrict__ bq,
                                                const float* __restrict__ bk,
                                                const float* __restrict__ bv,
                                                unsigned short* __restrict__ Qbf,
                                                unsigned short* __restrict__ Kbf,
                                                unsigned short* __restrict__ Vtb)
{
    __shared__ __attribute__((aligned(16))) unsigned short As[128 * 32];
    __shared__ __attribute__((aligned(16))) unsigned short Bs[128 * 32];

    const int tid = threadIdx.x;
    const int w = tid >> 6, lane = tid & 63;
    const int col = lane & 15, quad = lane >> 4;
    const int wm = (w >> 1) * 64, wn = (w & 1) * 64;
    const int m0 = blockIdx.y * 128, n0 = blockIdx.x * 128;

    f32x4 acc[4][4] = {};
    const int srow = tid >> 2, sc4 = tid & 3;

    for (int k0 = 0; k0 < DIM; k0 += 32) {
        __syncthreads();
#pragma unroll
        for (int it = 0; it < 2; it++) {
            gl_lds16(A  + (size_t)(m0 + srow + it * 64) * DIM + k0 + sc4 * 8,
                     (char*)As + w * 1024 + it * 4096);
            gl_lds16(Bt + (size_t)(n0 + srow + it * 64) * DIM + k0 + sc4 * 8,
                     (char*)Bs + w * 1024 + it * 4096);
        }
        __syncthreads();

        short8 af[4], bf[4];
#pragma unroll
        for (int mt = 0; mt < 4; mt++) af[mt] = *(short8*)&As[(wm + mt * 16 + col) * 32 + quad * 8];
#pragma unroll
        for (int nt = 0; nt < 4; nt++) bf[nt] = *(short8*)&Bs[(wn + nt * 16 + col) * 32 + quad * 8];

#pragma unroll
        for (int mt = 0; mt < 4; mt++)
#pragma unroll
            for (int nt = 0; nt < 4; nt++)
                acc[mt][nt] = __builtin_amdgcn_mfma_f32_16x16x32_bf16(af[mt], bf[nt], acc[mt][nt], 0, 0, 0);
    }

    const int sector = n0 >> 10;   // block never straddles (1024 % 128 == 0)
    const float* bias = (sector == 0) ? bq : (sector == 1) ? bk : bv;

#pragma unroll
    for (int nt = 0; nt < 4; nt++) {
        const int n = n0 + wn + nt * 16 + col;
        const int nloc = n - (sector << 10);
        const float bvv = bias[nloc];
#pragma unroll
        for (int mt = 0; mt < 4; mt++) {
            const int mbase = m0 + wm + mt * 16 + quad * 4;
            if (sector == 0) {
#pragma unroll
                for (int r = 0; r < 4; r++)
                    Qbf[(size_t)(mbase + r) * DIM + nloc] = f2bf((acc[mt][nt][r] + bvv) * QSCALE);
            } else if (sector == 1) {
#pragma unroll
                for (int r = 0; r < 4; r++)
                    Kbf[(size_t)(mbase + r) * DIM + nloc] = f2bf(acc[mt][nt][r] + bvv);
            } else {
                const int h = nloc >> 6, d = nloc & 63;
                const int b = mbase >> 11, l = mbase & 2047;
                ushort4 u;
                u.x = f2bf(acc[mt][nt][0] + bvv);
                u.y = f2bf(acc[mt][nt][1] + bvv);
                u.z = f2bf(acc[mt][nt][2] + bvv);
                u.w = f2bf(acc[mt][nt][3] + bvv);
                *(ushort4*)(Vtb + ((size_t)((b * NHEAD + h) * HDIM + d)) * SEQ + l) = u;
            }
        }
    }
}

// ---------------- out-proj GEMM: fp32 out = A @ Wot^T + bo + resid ----------------
__global__ __launch_bounds__(256) void gemm_out(const unsigned short* __restrict__ A,
                                                const unsigned short* __restrict__ Bt,
                                                const float* __restrict__ bias,
                                                const float* __restrict__ resid,
                                                float* __restrict__ Cout)
{
    __shared__ __attribute__((aligned(16))) unsigned short As[128 * 32];
    __shared__ __attribute__((aligned(16))) unsigned short Bs[128 * 32];

    const int tid = threadIdx.x;
    const int w = tid >> 6, lane = tid & 63;
    const int col = lane & 15, quad = lane >> 4;
    const int wm = (w >> 1) * 64, wn = (w & 1) * 64;
    const int m0 = blockIdx.y * 128, n0 = blockIdx.x * 128;

    f32x4 acc[4][4] = {};
    const int srow = tid >> 2, sc4 = tid & 3;

    for (int k0 = 0; k0 < DIM; k0 += 32) {
        __syncthreads();
#pragma unroll
        for (int it = 0; it < 2; it++) {
            gl_lds16(A  + (size_t)(m0 + srow + it * 64) * DIM + k0 + sc4 * 8,
                     (char*)As + w * 1024 + it * 4096);
            gl_lds16(Bt + (size_t)(n0 + srow + it * 64) * DIM + k0 + sc4 * 8,
                     (char*)Bs + w * 1024 + it * 4096);
        }
        __syncthreads();

        short8 af[4], bf[4];
#pragma unroll
        for (int mt = 0; mt < 4; mt++) af[mt] = *(short8*)&As[(wm + mt * 16 + col) * 32 + quad * 8];
#pragma unroll
        for (int nt = 0; nt < 4; nt++) bf[nt] = *(short8*)&Bs[(wn + nt * 16 + col) * 32 + quad * 8];

#pragma unroll
        for (int mt = 0; mt < 4; mt++)
#pragma unroll
            for (int nt = 0; nt < 4; nt++)
                acc[mt][nt] = __builtin_amdgcn_mfma_f32_16x16x32_bf16(af[mt], bf[nt], acc[mt][nt], 0, 0, 0);
    }

#pragma unroll
    for (int nt = 0; nt < 4; nt++) {
        const int n = n0 + wn + nt * 16 + col;
        const float bvv = bias[n];
#pragma unroll
        for (int mt = 0; mt < 4; mt++) {
            const int mbase = m0 + wm + mt * 16 + quad * 4;
#pragma unroll
            for (int r = 0; r < 4; r++) {
                const size_t off = (size_t)(mbase + r) * DIM + n;
                Cout[off] = acc[mt][nt][r] + bvv + resid[off];
            }
        }
    }
}

// ---------------- MFMA flash attention v16: 32x32 MFMA x 8 waves (d-split) ----------------
// Series model:
//  - v13 (16x16, 8 q-waves): 96.8us, LDS-read-bound (128 b128/block-kt, 82us).
//  - v15 (32x32, key-split):  104us. LDS halved (64 reads) but: epilogue
//    f32x16 exchange = 4-way bank conflicts (9.5e6) + 2 extra barriers, and
//    o[2] (32 acc regs) cut co-residency to 2 blocks/CU (occ 48->37%).
// v16: wave = (qw, dw). qw owns 32 q; dw owns a 32-row d-half of O.
//  - QK (both 32-key blocks) computed redundantly per dw-pair: MFMA is the
//    cheap pipe (43us budget); every wave then has the FULL per-q denominator
//    (dsum + shfl_xor 32, v14-verified) -> NO cross-wave merge, NO epilogue
//    exchange, NO extra barriers.
//  - PV only for own d-half: acc is ONE f32x16 (16 regs) -> ~70 regs/wave
//    -> 3 blocks/CU co-resident.
//  - LDS reads: 96 b128/block-kt (61us budget, 25% below v13).
//  - Staging/DMA/swizzle/double-buffer identical to v12b/v13 (32KB, zero
//    staging registers). All fragment layouts v14-hardware-verified.
__global__ __launch_bounds__(512) void attn_mfma(const unsigned short* __restrict__ Qb,
                                                 const unsigned short* __restrict__ Kb,
                                                 const unsigned short* __restrict__ Vt,
                                                 unsigned short* __restrict__ Ob)
{
    __shared__ __attribute__((aligned(16))) unsigned short Ks[2 * 64 * 64];  // [buf][key][d'] swizzled
    __shared__ __attribute__((aligned(16))) unsigned short Vs[2 * 64 * 64];  // [buf][d][key'] swizzled

    const int tid = threadIdx.x;
    const int w = tid >> 6, lane = tid & 63;     // w = 0..7
    const int qw = w & 3, dw = w >> 2;
    const int l31 = lane & 31, hi = lane >> 5;
    const int sw7 = l31 & 7;                 // read-side swizzle key (row&7)

    const int bh  = blockIdx.x & 63;   // (b,h) fastest -> q-blocks of one head share an XCD
    const int qt_ = blockIdx.x >> 6;
    const int b   = bh >> 4;
    const int h   = bh & 15;

    const int q0 = qt_ * 128 + qw * 32;   // 32 q-rows per qw group

    // Q B-fragments: col = q = l31, k = ds*16 + hi*8 + j
    short8 qf[4];
#pragma unroll
    for (int ds = 0; ds < 4; ds++)
        qf[ds] = *(const short8*)(Qb + ((size_t)(b * SEQ) + q0 + l31) * DIM + h * HDIM + ds * 16 + hi * 8);

    f32x16 o = {};       // O^T[d 32-half (dw)][q=32]
    float dsum = 0.f;    // per-lane softmax denominator partial (hi-half keys)

    const size_t kbase0 = ((size_t)(b * SEQ)) * DIM + h * HDIM;
    const size_t vbase0 = ((size_t)((b * NHEAD + h) * HDIM)) * SEQ;

    // DMA staging: wave w stages rows w*8 .. w*8+7 of K and of V (1 instr each).
    // Linear LDS dest, XOR-swizzled global source chunk (involution).
    const int lr  = lane >> 3;              // row-within-8 (== row&7)
    const int swc = (lane & 7) ^ lr;        // swizzled source chunk

    // prologue: DMA tile 0 into buf 0
    {
        const int row = w * 8 + lr;
        gl_lds16(Kb + kbase0 + (size_t)row * DIM + swc * 8, (char*)Ks + w * 1024);
        gl_lds16(Vt + vbase0 + (size_t)row * SEQ + swc * 8, (char*)Vs + w * 1024);
    }
    __syncthreads();

    for (int kt = 0; kt < SEQ / 64; kt++) {
        const int cur = kt & 1, nxt = cur ^ 1;
        const unsigned short* Ksb = Ks + cur * 4096;
        const unsigned short* Vsb = Vs + cur * 4096;

        // issue next tile's DMA now; latency hides under this tile's compute
        if (kt + 1 < SEQ / 64) {
            const int row = w * 8 + lr;
            gl_lds16(Kb + kbase0 + (size_t)((kt + 1) * 64 + row) * DIM + swc * 8,
                     (char*)Ks + nxt * 8192 + w * 1024);
            gl_lds16(Vt + vbase0 + (size_t)row * SEQ + (kt + 1) * 64 + swc * 8,
                     (char*)Vs + nxt * 8192 + w * 1024);
        }

        // per 32-key block: S^T = K @ Q^T ; P = 2^S ; PV for own d-half
#pragma unroll
        for (int kb = 0; kb < 2; kb++) {
            f32x16 s = {};
#pragma unroll
            for (int ds = 0; ds < 4; ds++) {
                short8 kf = *(const short8*)&Ksb[(kb * 32 + l31) * 64 + (((ds * 2 + hi) ^ sw7) * 8)];
                s = __builtin_amdgcn_mfma_f32_32x32x16_bf16(kf, qf[ds], s, 0, 0, 0);
            }
            // exp2 + f32 denominator partial + pack to bf16 pairs
            unsigned d0, d1, d2, d3, d4, d5, d6, d7;
            {
                float p0, p1;
                p0 = __builtin_amdgcn_exp2f(s[0]);  p1 = __builtin_amdgcn_exp2f(s[1]);
                dsum += p0 + p1;  d0 = pack2bf(p0, p1);
                p0 = __builtin_amdgcn_exp2f(s[2]);  p1 = __builtin_amdgcn_exp2f(s[3]);
                dsum += p0 + p1;  d1 = pack2bf(p0, p1);
                p0 = __builtin_amdgcn_exp2f(s[4]);  p1 = __builtin_amdgcn_exp2f(s[5]);
                dsum += p0 + p1;  d2 = pack2bf(p0, p1);
                p0 = __builtin_amdgcn_exp2f(s[6]);  p1 = __builtin_amdgcn_exp2f(s[7]);
                dsum += p0 + p1;  d3 = pack2bf(p0, p1);
                p0 = __builtin_amdgcn_exp2f(s[8]);  p1 = __builtin_amdgcn_exp2f(s[9]);
                dsum += p0 + p1;  d4 = pack2bf(p0, p1);
                p0 = __builtin_amdgcn_exp2f(s[10]); p1 = __builtin_amdgcn_exp2f(s[11]);
                dsum += p0 + p1;  d5 = pack2bf(p0, p1);
                p0 = __builtin_amdgcn_exp2f(s[12]); p1 = __builtin_amdgcn_exp2f(s[13]);
                dsum += p0 + p1;  d6 = pack2bf(p0, p1);
                p0 = __builtin_amdgcn_exp2f(s[14]); p1 = __builtin_amdgcn_exp2f(s[15]);
                dsum += p0 + p1;  d7 = pack2bf(p0, p1);
            }
            // reshape to PV B-fragments (v14-verified): 4 permlane32_swap,
            // then {d0..d3},{d4..d7} are the keyslice-0/1 fragments verbatim.
            pl32_swap(d0, d2);  pl32_swap(d1, d3);
            pl32_swap(d4, d6);  pl32_swap(d5, d7);
            short8 pf0 = __builtin_bit_cast(short8, uint32x4{d0, d1, d2, d3});
            short8 pf1 = __builtin_bit_cast(short8, uint32x4{d4, d5, d6, d7});

            __builtin_amdgcn_s_setprio(1);
            // O^T += V^T @ P^T for own d-half: A = V^T[d dw-half][key kb-block]
            {
                short8 vf0 = *(const short8*)&Vsb[(dw * 32 + l31) * 64 + (((kb * 4 + 0 + hi) ^ sw7) * 8)];
                short8 vf1 = *(const short8*)&Vsb[(dw * 32 + l31) * 64 + (((kb * 4 + 2 + hi) ^ sw7) * 8)];
                o = __builtin_amdgcn_mfma_f32_32x32x16_bf16(vf0, pf0, o, 0, 0, 0);
                o = __builtin_amdgcn_mfma_f32_32x32x16_bf16(vf1, pf1, o, 0, 0, 0);
            }
            __builtin_amdgcn_s_setprio(0);
        }

        // drains vmcnt (next tile's DMA landed) + lgkmcnt (this tile's reads done)
        __syncthreads();
    }

    // denominator: lane halves hold complementary key sets (full 64-key range
    // accumulated over both kb blocks each iteration)
    const float den = dsum + __shfl_xor(dsum, 32);
    const float inv = 1.f / den;

    // O^T layout: col = q = l31, row-within-half = (reg&3) + 8*(reg>>2) + 4*hi
    const size_t rowoff = ((size_t)(b * SEQ) + q0 + l31) * DIM + h * HDIM;
#pragma unroll
    for (int g = 0; g < 4; g++) {
        ushort4 u;
        u.x = f2bf(o[g * 4 + 0] * inv);
        u.y = f2bf(o[g * 4 + 1] * inv);
        u.z = f2bf(o[g * 4 + 2] * inv);
        u.w = f2bf(o[g * 4 + 3] * inv);
        *(ushort4*)(Ob + rowoff + dw * 32 + g * 8 + hi * 4) = u;
    }
}

// ---------------- LayerNorm (in-place on d_out) ----------------
__global__ __launch_bounds__(256) void layernorm_kernel(float* __restrict__ res,
                                                        const float* __restrict__ gamma,
                                                        const float* __restrict__ beta)
{
    const int tid = threadIdx.x;
    const int row = blockIdx.x;
    float4 xv = ((const float4*)(res + (size_t)row * DIM))[tid];

    float s  = xv.x + xv.y + xv.z + xv.w;
    float sq = xv.x * xv.x + xv.y * xv.y + xv.z * xv.z + xv.w * xv.w;
#pragma unroll
    for (int off = 32; off; off >>= 1) {
        s  += __shfl_xor(s, off);
        sq += __shfl_xor(sq, off);
    }
    __shared__ float sm[8];
    const int w = tid >> 6, lane = tid & 63;
    if (lane == 0) { sm[w] = s; sm[4 + w] = sq; }
    __syncthreads();
    const float st  = sm[0] + sm[1] + sm[2] + sm[3];
    const float sqt = sm[4] + sm[5] + sm[6] + sm[7];
    const float mu   = st * (1.f / DIM);
    const float var  = sqt * (1.f / DIM) - mu * mu;
    const float rstd = rsqrtf(var + EPS_LN);

    float4 g  = ((const float4*)gamma)[tid];
    float4 be = ((const float4*)beta)[tid];
    float4 o;
    o.x = (xv.x - mu) * rstd * g.x + be.x;
    o.y = (xv.y - mu) * rstd * g.y + be.y;
    o.z = (xv.z - mu) * rstd * g.z + be.z;
    o.w = (xv.w - mu) * rstd * g.w + be.w;
    ((float4*)(res + (size_t)row * DIM))[tid] = o;
}

// ---------------- launch ----------------
extern "C" void kernel_launch(void* const* d_in, const int* in_sizes, int n_in,
                              void* d_out, int out_size, void* d_ws, size_t ws_size,
                              hipStream_t stream)
{
    const float* queries = (const float*)d_in[0];
    const float* Wq = (const float*)d_in[1];
    const float* bq = (const float*)d_in[2];
    const float* Wk = (const float*)d_in[3];
    const float* bk = (const float*)d_in[4];
    const float* Wv = (const float*)d_in[5];
    const float* bv = (const float*)d_in[6];
    const float* Wo = (const float*)d_in[7];
    const float* bo = (const float*)d_in[8];
    const float* gamma = (const float*)d_in[9];
    const float* beta  = (const float*)d_in[10];
    float* outp = (float*)d_out;

    const int M = BATCH * SEQ;                    // 8192
    const size_t BUF = (size_t)M * DIM;
    const size_t WSZ = (size_t)DIM * DIM;

    unsigned short* w0  = (unsigned short*)d_ws;
    unsigned short* qin = w0;                     // bf16 queries; later: attention output
    unsigned short* Qbf = w0 + BUF;
    unsigned short* Kbf = w0 + 2 * BUF;
    unsigned short* Vtb = w0 + 3 * BUF;
    unsigned short* Wqkvt = w0 + 4 * BUF;         // [3072][1024]
    unsigned short* Wot   = Wqkvt + 3 * WSZ;
    unsigned short* Obf = qin;                    // reuse

    dim3 blk(256);

    // z=0..3: weight transposes; z=4: queries fp32->bf16
    dim3 pgrid(DIM / 64, DIM / 64, 5);
    prep_kernel<<<pgrid, blk, 0, stream>>>(Wq, Wk, Wv, Wo, queries, Wqkvt, Wot, qin);

    dim3 qkvgrid(3 * DIM / 128, M / 128);         // (24, 64) = 1536 blocks
    gemm_qkv<<<qkvgrid, blk, 0, stream>>>(qin, Wqkvt, bq, bk, bv, Qbf, Kbf, Vtb);

    // 1024 blocks x 512 threads: swizzled decode (bh = idx & 63, qt = idx >> 6)
    attn_mfma<<<BATCH * NHEAD * (SEQ / 128), dim3(512), 0, stream>>>(Qbf, Kbf, Vtb, Obf);

    dim3 ogrid(DIM / 128, M / 128);               // (8, 64)
    gemm_out<<<ogrid, blk, 0, stream>>>(Obf, Wot, bo, queries, outp);

    layernorm_kernel<<<M, blk, 0, stream>>>(outp, gamma, beta);
}

// Round 10
// 305.490 us; speedup vs baseline: 1.1838x; 1.1838x over previous
//
#include <hip/hip_runtime.h>
#include <hip/hip_bf16.h>

// Problem constants
#define BATCH 4
#define SEQ   2048
#define DIM   1024      // D = H*HDIM
#define NHEAD 16
#define HDIM  64
#define EPS_LN 1e-5f
// 1/sqrt(64) * log2(e): folded into Q projection so attention can use exp2
#define QSCALE 0.18033688011112042f

typedef __attribute__((ext_vector_type(8))) short short8;   // 8 bf16 = 4 VGPR
typedef __attribute__((ext_vector_type(4))) float f32x4;    // MFMA acc
typedef __attribute__((ext_vector_type(4))) unsigned uint32x4;

__device__ __forceinline__ unsigned short f2bf(float x) {
    __hip_bfloat16 h = __float2bfloat16(x);
    return *reinterpret_cast<unsigned short*>(&h);
}
__device__ __forceinline__ unsigned int pack2bf(float a, float b) {
    __hip_bfloat162 h = __float22bfloat162_rn(float2{a, b});
    return *reinterpret_cast<unsigned int*>(&h);
}

// gfx950 register-pair lane swaps (both operands are read-modify-write).
// v_permlane32_swap_b32: vdst[32:63] <-> src[0:31]
// v_permlane16_swap_b32: rows 1,3 (lanes 16-31,48-63) of vdst <-> rows 0,2 of src
__device__ __forceinline__ void pl32_swap(unsigned& a, unsigned& b) {
    asm("v_permlane32_swap_b32 %0, %1" : "+v"(a), "+v"(b));
}
__device__ __forceinline__ void pl16_swap(unsigned& a, unsigned& b) {
    asm("v_permlane16_swap_b32 %0, %1" : "+v"(a), "+v"(b));
}

// async 16B global -> LDS (per-lane gptr; LDS dest must be wave-uniform-base + lane*16)
__device__ __forceinline__ void gl_lds16(const void* g, void* l) {
    __builtin_amdgcn_global_load_lds(
        (const __attribute__((address_space(1))) unsigned int*)g,
        (__attribute__((address_space(3))) unsigned int*)l,
        16, 0, 0);
}

// ---------------- prep: 4 weight transposes (z=0..3) + queries convert (z=4) ----------------
__global__ __launch_bounds__(256) void prep_kernel(const float* __restrict__ W0,
                                                   const float* __restrict__ W1,
                                                   const float* __restrict__ W2,
                                                   const float* __restrict__ W3,
                                                   const float* __restrict__ queries,
                                                   unsigned short* __restrict__ Wqkvt,
                                                   unsigned short* __restrict__ Wot,
                                                   unsigned short* __restrict__ qout)
{
    const int z = blockIdx.z;
    const int t = threadIdx.x;

    if (z == 4) {
        // bulk fp32 -> bf16 convert of queries
        const int nthr = 16 * 16 * 256;            // 65536
        int i = (blockIdx.y * 16 + blockIdx.x) * 256 + t;
        for (int it = 0; it < (BATCH * SEQ * DIM / 4) / nthr; it++, i += nthr) {
            float4 v = ((const float4*)queries)[i];
            ushort4 u;
            u.x = f2bf(v.x); u.y = f2bf(v.y); u.z = f2bf(v.z); u.w = f2bf(v.w);
            ((ushort4*)qout)[i] = u;
        }
        return;
    }

    __shared__ float Ts[64][65];
    const float* W = (z == 0) ? W0 : (z == 1) ? W1 : (z == 2) ? W2 : W3;
    unsigned short* Wt = (z == 3) ? Wot : (Wqkvt + (size_t)z * DIM * DIM);

    const int k0 = blockIdx.y * 64, n0 = blockIdx.x * 64;
    const int lr = t >> 2, lq = t & 3;

#pragma unroll
    for (int i = 0; i < 4; i++) {
        float4 v = *(const float4*)(W + (size_t)(k0 + lr) * DIM + n0 + (lq * 4 + i) * 4);
        Ts[lr][(lq * 4 + i) * 4 + 0] = v.x;
        Ts[lr][(lq * 4 + i) * 4 + 1] = v.y;
        Ts[lr][(lq * 4 + i) * 4 + 2] = v.z;
        Ts[lr][(lq * 4 + i) * 4 + 3] = v.w;
    }
    __syncthreads();
#pragma unroll
    for (int i = 0; i < 4; i++) {
        const int c = lq * 16 + i * 4;
        ushort4 u;
        u.x = f2bf(Ts[c + 0][lr]);
        u.y = f2bf(Ts[c + 1][lr]);
        u.z = f2bf(Ts[c + 2][lr]);
        u.w = f2bf(Ts[c + 3][lr]);
        *(ushort4*)(Wt + (size_t)(n0 + lr) * DIM + k0 + c) = u;
    }
}

// ---------------- fused QKV GEMM: [8192,1024] @ [3072,1024]^T ----------------
// sector 0: Qbf natural bf16, (acc+bq)*QSCALE
// sector 1: Kbf natural bf16, acc+bk
// sector 2: Vtb transposed-per-head: Vt[b][h][d][l], acc+bv
__global__ __launch_bounds__(256) void gemm_qkv(const unsigned short* __restrict__ A,
                                                const unsigned short* __restrict__ Bt,
                                                const float* __restrict__ bq,
                                                const float* __restrict__ bk,
                                                const float* __restrict__ bv,
                                                unsigned short* __restrict__ Qbf,
                                                unsigned short* __restrict__ Kbf,
                                                unsigned short* __restrict__ Vtb)
{
    __shared__ __attribute__((aligned(16))) unsigned short As[128 * 32];
    __shared__ __attribute__((aligned(16))) unsigned short Bs[128 * 32];

    const int tid = threadIdx.x;
    const int w = tid >> 6, lane = tid & 63;
    const int col = lane & 15, quad = lane >> 4;
    const int wm = (w >> 1) * 64, wn = (w & 1) * 64;
    const int m0 = blockIdx.y * 128, n0 = blockIdx.x * 128;

    f32x4 acc[4][4] = {};
    const int srow = tid >> 2, sc4 = tid & 3;

    for (int k0 = 0; k0 < DIM; k0 += 32) {
        __syncthreads();
#pragma unroll
        for (int it = 0; it < 2; it++) {
            gl_lds16(A  + (size_t)(m0 + srow + it * 64) * DIM + k0 + sc4 * 8,
                     (char*)As + w * 1024 + it * 4096);
            gl_lds16(Bt + (size_t)(n0 + srow + it * 64) * DIM + k0 + sc4 * 8,
                     (char*)Bs + w * 1024 + it * 4096);
        }
        __syncthreads();

        short8 af[4], bf[4];
#pragma unroll
        for (int mt = 0; mt < 4; mt++) af[mt] = *(short8*)&As[(wm + mt * 16 + col) * 32 + quad * 8];
#pragma unroll
        for (int nt = 0; nt < 4; nt++) bf[nt] = *(short8*)&Bs[(wn + nt * 16 + col) * 32 + quad * 8];

#pragma unroll
        for (int mt = 0; mt < 4; mt++)
#pragma unroll
            for (int nt = 0; nt < 4; nt++)
                acc[mt][nt] = __builtin_amdgcn_mfma_f32_16x16x32_bf16(af[mt], bf[nt], acc[mt][nt], 0, 0, 0);
    }

    const int sector = n0 >> 10;   // block never straddles (1024 % 128 == 0)
    const float* bias = (sector == 0) ? bq : (sector == 1) ? bk : bv;

#pragma unroll
    for (int nt = 0; nt < 4; nt++) {
        const int n = n0 + wn + nt * 16 + col;
        const int nloc = n - (sector << 10);
        const float bvv = bias[nloc];
#pragma unroll
        for (int mt = 0; mt < 4; mt++) {
            const int mbase = m0 + wm + mt * 16 + quad * 4;
            if (sector == 0) {
#pragma unroll
                for (int r = 0; r < 4; r++)
                    Qbf[(size_t)(mbase + r) * DIM + nloc] = f2bf((acc[mt][nt][r] + bvv) * QSCALE);
            } else if (sector == 1) {
#pragma unroll
                for (int r = 0; r < 4; r++)
                    Kbf[(size_t)(mbase + r) * DIM + nloc] = f2bf(acc[mt][nt][r] + bvv);
            } else {
                const int h = nloc >> 6, d = nloc & 63;
                const int b = mbase >> 11, l = mbase & 2047;
                ushort4 u;
                u.x = f2bf(acc[mt][nt][0] + bvv);
                u.y = f2bf(acc[mt][nt][1] + bvv);
                u.z = f2bf(acc[mt][nt][2] + bvv);
                u.w = f2bf(acc[mt][nt][3] + bvv);
                *(ushort4*)(Vtb + ((size_t)((b * NHEAD + h) * HDIM + d)) * SEQ + l) = u;
            }
        }
    }
}

// ---------------- out-proj GEMM: fp32 out = A @ Wot^T + bo + resid ----------------
__global__ __launch_bounds__(256) void gemm_out(const unsigned short* __restrict__ A,
                                                const unsigned short* __restrict__ Bt,
                                                const float* __restrict__ bias,
                                                const float* __restrict__ resid,
                                                float* __restrict__ Cout)
{
    __shared__ __attribute__((aligned(16))) unsigned short As[128 * 32];
    __shared__ __attribute__((aligned(16))) unsigned short Bs[128 * 32];

    const int tid = threadIdx.x;
    const int w = tid >> 6, lane = tid & 63;
    const int col = lane & 15, quad = lane >> 4;
    const int wm = (w >> 1) * 64, wn = (w & 1) * 64;
    const int m0 = blockIdx.y * 128, n0 = blockIdx.x * 128;

    f32x4 acc[4][4] = {};
    const int srow = tid >> 2, sc4 = tid & 3;

    for (int k0 = 0; k0 < DIM; k0 += 32) {
        __syncthreads();
#pragma unroll
        for (int it = 0; it < 2; it++) {
            gl_lds16(A  + (size_t)(m0 + srow + it * 64) * DIM + k0 + sc4 * 8,
                     (char*)As + w * 1024 + it * 4096);
            gl_lds16(Bt + (size_t)(n0 + srow + it * 64) * DIM + k0 + sc4 * 8,
                     (char*)Bs + w * 1024 + it * 4096);
        }
        __syncthreads();

        short8 af[4], bf[4];
#pragma unroll
        for (int mt = 0; mt < 4; mt++) af[mt] = *(short8*)&As[(wm + mt * 16 + col) * 32 + quad * 8];
#pragma unroll
        for (int nt = 0; nt < 4; nt++) bf[nt] = *(short8*)&Bs[(wn + nt * 16 + col) * 32 + quad * 8];

#pragma unroll
        for (int mt = 0; mt < 4; mt++)
#pragma unroll
            for (int nt = 0; nt < 4; nt++)
                acc[mt][nt] = __builtin_amdgcn_mfma_f32_16x16x32_bf16(af[mt], bf[nt], acc[mt][nt], 0, 0, 0);
    }

#pragma unroll
    for (int nt = 0; nt < 4; nt++) {
        const int n = n0 + wn + nt * 16 + col;
        const float bvv = bias[n];
#pragma unroll
        for (int mt = 0; mt < 4; mt++) {
            const int mbase = m0 + wm + mt * 16 + quad * 4;
#pragma unroll
            for (int r = 0; r < 4; r++) {
                const size_t off = (size_t)(mbase + r) * DIM + n;
                Cout[off] = acc[mt][nt][r] + bvv + resid[off];
            }
        }
    }
}

// ---------------- MFMA flash attention v17: v12b body x 8 waves, 32 q/wave ----------------
// Series: v13 (8 waves x 16q, 16x16) = 96.8us champion, LDS-read-bound
// (~55us of LDS demand: q-waves re-read identical K/V fragments).
// v16 (d-split) doubled VALU -> 153us. 32x32 variants all carry unexplained
// conflicts (8.4-12.6e6) -> abandoned.
// v17: K/V fragment reads are q-independent -> a wave serving TWO q-tiles
// (32 q, qt loop) reuses the same 16 b128 reads -> per-q LDS traffic HALVES
// with the conflict-free 16x16 ca/cb pattern. This is the v12b wave body
// VERBATIM (hardware-proven: VGPR 80, 0 conflicts, passed) at 8 waves /
// 512-thread blocks; grid 512 (q-tile 256 per block).
// Staging/DMA/swizzle/double-buffer = v13's (1 gl_lds16 per wave per array).
// Per-dispatch LDS reads: 4.2M -> 2.1M b128. VALU (~51us) becomes top pipe.
__global__ __launch_bounds__(512) void attn_mfma(const unsigned short* __restrict__ Qb,
                                                 const unsigned short* __restrict__ Kb,
                                                 const unsigned short* __restrict__ Vt,
                                                 unsigned short* __restrict__ Ob)
{
    __shared__ __attribute__((aligned(16))) unsigned short Ks[2 * 64 * 64];  // [buf][key][d'] swizzled
    __shared__ __attribute__((aligned(16))) unsigned short Vs[2 * 64 * 64];  // [buf][d][key'] swizzled

    const int tid = threadIdx.x;
    const int w = tid >> 6, lane = tid & 63;     // w = 0..7
    const int col = lane & 15, quad = lane >> 4;
    const int cs  = col & 7;            // read-side swizzle key (row&7 == col&7 for all frag rows)
    const int ca  = quad ^ cs;          // chunk holding halfs quad*8 .. +7
    const int cb  = (quad ^ 4) ^ cs;    // chunk holding halfs quad*8+32 .. +39

    const int bh  = blockIdx.x & 63;   // (b,h) fastest -> q-blocks of one head share an XCD
    const int qt_ = blockIdx.x >> 6;   // 0..7 (q-tile of 256)
    const int b   = bh >> 4;
    const int h   = bh & 15;

    const int q0 = qt_ * 256 + w * 32;   // 32 q-rows per wave

    // Q B-fragments (two 16-row tiles per wave)
    short8 qf[2][2];
#pragma unroll
    for (int qt = 0; qt < 2; qt++) {
        const size_t base = ((size_t)(b * SEQ) + q0 + qt * 16 + col) * DIM + h * HDIM + quad * 8;
        qf[qt][0] = *(const short8*)(Qb + base);
        qf[qt][1] = *(const short8*)(Qb + base + 32);
    }

    // ones A-fragment (row 0 = key-sum of P)
    short8 onesf;
    {
        const short v = (col == 0) ? (short)0x3F80 : (short)0;
        onesf = short8{v, v, v, v, v, v, v, v};
    }

    f32x4 o[4][2] = {};
    f32x4 od[2]   = {};

    const size_t kbase0 = ((size_t)(b * SEQ)) * DIM + h * HDIM;
    const size_t vbase0 = ((size_t)((b * NHEAD + h) * HDIM)) * SEQ;

    // DMA staging: wave w stages rows w*8 .. w*8+7 of K and of V (1 instr each).
    // Linear LDS dest, XOR-swizzled global source chunk (involution).
    const int lr  = lane >> 3;              // row-within-8 (== row&7)
    const int swc = (lane & 7) ^ lr;        // swizzled source chunk

    // prologue: DMA tile 0 into buf 0
    {
        const int row = w * 8 + lr;
        gl_lds16(Kb + kbase0 + (size_t)row * DIM + swc * 8, (char*)Ks + w * 1024);
        gl_lds16(Vt + vbase0 + (size_t)row * SEQ + swc * 8, (char*)Vs + w * 1024);
    }
    __syncthreads();

    for (int kt = 0; kt < SEQ / 64; kt++) {
        const int cur = kt & 1, nxt = cur ^ 1;
        const unsigned short* Ksb = Ks + cur * 4096;
        const unsigned short* Vsb = Vs + cur * 4096;

        // issue next tile's DMA now; latency hides under this tile's compute
        if (kt + 1 < SEQ / 64) {
            const int row = w * 8 + lr;
            gl_lds16(Kb + kbase0 + (size_t)((kt + 1) * 64 + row) * DIM + swc * 8,
                     (char*)Ks + nxt * 8192 + w * 1024);
            gl_lds16(Vt + vbase0 + (size_t)row * SEQ + (kt + 1) * 64 + swc * 8,
                     (char*)Vs + nxt * 8192 + w * 1024);
        }

        // S^T = K @ Q^T ; P = 2^S ; reshape P to PV B-fragments fully in registers.
        short8 pf[2][2];
#pragma unroll
        for (int f = 0; f < 2; f++) {
            short8 kfe0 = *(short8*)&Ksb[((f * 2 + 0) * 16 + col) * 64 + ca * 8];
            short8 kfe1 = *(short8*)&Ksb[((f * 2 + 0) * 16 + col) * 64 + cb * 8];
            short8 kfo0 = *(short8*)&Ksb[((f * 2 + 1) * 16 + col) * 64 + ca * 8];
            short8 kfo1 = *(short8*)&Ksb[((f * 2 + 1) * 16 + col) * 64 + cb * 8];
#pragma unroll
            for (int qt = 0; qt < 2; qt++) {
                f32x4 se = {};
                se = __builtin_amdgcn_mfma_f32_16x16x32_bf16(kfe0, qf[qt][0], se, 0, 0, 0);
                se = __builtin_amdgcn_mfma_f32_16x16x32_bf16(kfe1, qf[qt][1], se, 0, 0, 0);
                f32x4 so = {};
                so = __builtin_amdgcn_mfma_f32_16x16x32_bf16(kfo0, qf[qt][0], so, 0, 0, 0);
                so = __builtin_amdgcn_mfma_f32_16x16x32_bf16(kfo1, qf[qt][1], so, 0, 0, 0);

                unsigned a0 = pack2bf(__builtin_amdgcn_exp2f(se[0]), __builtin_amdgcn_exp2f(se[1]));
                unsigned b0 = pack2bf(__builtin_amdgcn_exp2f(se[2]), __builtin_amdgcn_exp2f(se[3]));
                unsigned a1 = pack2bf(__builtin_amdgcn_exp2f(so[0]), __builtin_amdgcn_exp2f(so[1]));
                unsigned b1 = pack2bf(__builtin_amdgcn_exp2f(so[2]), __builtin_amdgcn_exp2f(so[3]));

                pl32_swap(a0, a1);   // pair even/odd nt across lane halves
                pl32_swap(b0, b1);
                pl16_swap(a0, a1);   // quad exchange 0<->1, 2<->3
                pl16_swap(b0, b1);

                uint32x4 cv = {a0, b0, a1, b1};
                pf[qt][f] = __builtin_bit_cast(short8, cv);
            }
        }

        __builtin_amdgcn_s_setprio(1);
        // denominator rows (ones A-fragment MFMA)
#pragma unroll
        for (int qt = 0; qt < 2; qt++) {
            od[qt] = __builtin_amdgcn_mfma_f32_16x16x32_bf16(onesf, pf[qt][0], od[qt], 0, 0, 0);
            od[qt] = __builtin_amdgcn_mfma_f32_16x16x32_bf16(onesf, pf[qt][1], od[qt], 0, 0, 0);
        }

        // O^T += V^T @ P^T (V-fragments read ONCE, reused for both qt)
#pragma unroll
        for (int mt = 0; mt < 4; mt++) {
            short8 vf0 = *(short8*)&Vsb[(mt * 16 + col) * 64 + ca * 8];
            short8 vf1 = *(short8*)&Vsb[(mt * 16 + col) * 64 + cb * 8];
#pragma unroll
            for (int qt = 0; qt < 2; qt++) {
                o[mt][qt] = __builtin_amdgcn_mfma_f32_16x16x32_bf16(vf0, pf[qt][0], o[mt][qt], 0, 0, 0);
                o[mt][qt] = __builtin_amdgcn_mfma_f32_16x16x32_bf16(vf1, pf[qt][1], o[mt][qt], 0, 0, 0);
            }
        }
        __builtin_amdgcn_s_setprio(0);

        // drains vmcnt (next tile's DMA landed) + lgkmcnt (this tile's reads done)
        __syncthreads();
    }

    // denom for q=col lives in od[qt][0] on quad-0 lane #col; broadcast
#pragma unroll
    for (int qt = 0; qt < 2; qt++) {
        const float den = __shfl(od[qt][0], col);
        const float inv = 1.f / den;
        const size_t rowoff = ((size_t)(b * SEQ) + q0 + qt * 16 + col) * DIM + h * HDIM;
#pragma unroll
        for (int mt = 0; mt < 4; mt++) {
            ushort4 u;
            u.x = f2bf(o[mt][qt][0] * inv);
            u.y = f2bf(o[mt][qt][1] * inv);
            u.z = f2bf(o[mt][qt][2] * inv);
            u.w = f2bf(o[mt][qt][3] * inv);
            *(ushort4*)(Ob + rowoff + mt * 16 + quad * 4) = u;
        }
    }
}

// ---------------- LayerNorm (in-place on d_out) ----------------
__global__ __launch_bounds__(256) void layernorm_kernel(float* __restrict__ res,
                                                        const float* __restrict__ gamma,
                                                        const float* __restrict__ beta)
{
    const int tid = threadIdx.x;
    const int row = blockIdx.x;
    float4 xv = ((const float4*)(res + (size_t)row * DIM))[tid];

    float s  = xv.x + xv.y + xv.z + xv.w;
    float sq = xv.x * xv.x + xv.y * xv.y + xv.z * xv.z + xv.w * xv.w;
#pragma unroll
    for (int off = 32; off; off >>= 1) {
        s  += __shfl_xor(s, off);
        sq += __shfl_xor(sq, off);
    }
    __shared__ float sm[8];
    const int w = tid >> 6, lane = tid & 63;
    if (lane == 0) { sm[w] = s; sm[4 + w] = sq; }
    __syncthreads();
    const float st  = sm[0] + sm[1] + sm[2] + sm[3];
    const float sqt = sm[4] + sm[5] + sm[6] + sm[7];
    const float mu   = st * (1.f / DIM);
    const float var  = sqt * (1.f / DIM) - mu * mu;
    const float rstd = rsqrtf(var + EPS_LN);

    float4 g  = ((const float4*)gamma)[tid];
    float4 be = ((const float4*)beta)[tid];
    float4 o;
    o.x = (xv.x - mu) * rstd * g.x + be.x;
    o.y = (xv.y - mu) * rstd * g.y + be.y;
    o.z = (xv.z - mu) * rstd * g.z + be.z;
    o.w = (xv.w - mu) * rstd * g.w + be.w;
    ((float4*)(res + (size_t)row * DIM))[tid] = o;
}

// ---------------- launch ----------------
extern "C" void kernel_launch(void* const* d_in, const int* in_sizes, int n_in,
                              void* d_out, int out_size, void* d_ws, size_t ws_size,
                              hipStream_t stream)
{
    const float* queries = (const float*)d_in[0];
    const float* Wq = (const float*)d_in[1];
    const float* bq = (const float*)d_in[2];
    const float* Wk = (const float*)d_in[3];
    const float* bk = (const float*)d_in[4];
    const float* Wv = (const float*)d_in[5];
    const float* bv = (const float*)d_in[6];
    const float* Wo = (const float*)d_in[7];
    const float* bo = (const float*)d_in[8];
    const float* gamma = (const float*)d_in[9];
    const float* beta  = (const float*)d_in[10];
    float* outp = (float*)d_out;

    const int M = BATCH * SEQ;                    // 8192
    const size_t BUF = (size_t)M * DIM;
    const size_t WSZ = (size_t)DIM * DIM;

    unsigned short* w0  = (unsigned short*)d_ws;
    unsigned short* qin = w0;                     // bf16 queries; later: attention output
    unsigned short* Qbf = w0 + BUF;
    unsigned short* Kbf = w0 + 2 * BUF;
    unsigned short* Vtb = w0 + 3 * BUF;
    unsigned short* Wqkvt = w0 + 4 * BUF;         // [3072][1024]
    unsigned short* Wot   = Wqkvt + 3 * WSZ;
    unsigned short* Obf = qin;                    // reuse

    dim3 blk(256);

    // z=0..3: weight transposes; z=4: queries fp32->bf16
    dim3 pgrid(DIM / 64, DIM / 64, 5);
    prep_kernel<<<pgrid, blk, 0, stream>>>(Wq, Wk, Wv, Wo, queries, Wqkvt, Wot, qin);

    dim3 qkvgrid(3 * DIM / 128, M / 128);         // (24, 64) = 1536 blocks
    gemm_qkv<<<qkvgrid, blk, 0, stream>>>(qin, Wqkvt, bq, bk, bv, Qbf, Kbf, Vtb);

    // 512 blocks x 512 threads: swizzled decode (bh = idx & 63, qt = idx >> 6)
    attn_mfma<<<BATCH * NHEAD * (SEQ / 256), dim3(512), 0, stream>>>(Qbf, Kbf, Vtb, Obf);

    dim3 ogrid(DIM / 128, M / 128);               // (8, 64)
    gemm_out<<<ogrid, blk, 0, stream>>>(Obf, Wot, bo, queries, outp);

    layernorm_kernel<<<M, blk, 0, stream>>>(outp, gamma, beta);
}